// Round 12
// baseline (102.802 us; speedup 1.0000x reference)
//
#include <hip/hip_runtime.h>
#include <math.h>

#define D_DIM 128
#define A_DIM 128
#define SPLIT 4            // contiguous quarters per segment
#define NTHREADS 256       // 4 waves per block
#define NWAVES 4
#define PSTRIDE 132        // floats per partial record: o[128], den, pad

typedef _Float16 f16x8 __attribute__((ext_vector_type(8)));
typedef __fp16   fp16x2 __attribute__((ext_vector_type(2)));  // cvt_pkrtz return type
typedef __attribute__((ext_vector_type(4))) float f32x4;

__device__ __forceinline__ float fast_tanh(float v) {
    float e = __expf(2.0f * v);
    return 1.0f - 2.0f * __builtin_amdgcn_rcpf(e + 1.0f);
}

__device__ __forceinline__ int lower_bound_i32(const int* __restrict__ arr, int n, int val) {
    int lo = 0, hi = n;
    while (lo < hi) {
        int mid = (lo + hi) >> 1;
        if (arr[mid] < val) lo = mid + 1; else hi = mid;
    }
    return lo;
}

// K0: parallel segment bounds (bidx sorted)
extern "C" __global__ void __launch_bounds__(256)
seg_bounds_kernel(const int* __restrict__ bidx, int N, int B,
                  int* __restrict__ seg_start)
{
    const int i = blockIdx.x * 256 + threadIdx.x;
    if (i <= B) seg_start[i] = lower_bound_i32(bidx, N, i);
}

// K1: per-(segment, contiguous quarter) unnormalized partial, barrier-free.
// R10 changes vs R9 (VALU diet, ~2x fewer ops/byte):
//  - single fp16 MFMA term (al dropped): score err ~1e-3 pre-exp, harmless
//  - f32 double-buffer bufA/bufB: o_part accumulates exact f32 x (32 fmaf,
//    no fp16 re-materialization, no added output quantization)
//  - packed v_cvt_pkrtz f32->f16 hi-split (16 ops vs 128)
extern "C" __global__ void __launch_bounds__(NTHREADS)
fused_partial_kernel(const float* __restrict__ x,
                     const int* __restrict__ seg_start,
                     const float* __restrict__ W1,
                     const float* __restrict__ b1,
                     const float* __restrict__ W2,
                     float* __restrict__ part,
                     int N)
{
    __shared__ _Float16 w1s[A_DIM * D_DIM];   // 32 KB, [col][k] XOR-swizzled
    __shared__ float sB1[A_DIM];
    __shared__ float sW2[A_DIM];
    __shared__ float s_sc[NWAVES * 16];       // per-wave own-row score slots
    __shared__ float o_red[NWAVES * 4 * 32];  // 2 KB epilogue reduce
    __shared__ float s_d[NWAVES];

    const int tid = threadIdx.x;
    const int b   = blockIdx.x >> 2;          // segment  (SPLIT = 4)
    const int q   = blockIdx.x & (SPLIT - 1); // quarter

    if (tid < A_DIM) { sB1[tid] = b1[tid]; sW2[tid] = W2[tid]; }

    // stage W1: read coalesced [k][c], write transposed+swizzled fp16
    for (int item = tid; item < A_DIM * 16; item += NTHREADS) {
        const int c = item & (A_DIM - 1);
        const int chunk = item >> 7;          // 16B chunk along k (0..15)
        f16x8 vh;
        #pragma unroll
        for (int j = 0; j < 8; ++j)
            vh[j] = (_Float16)W1[(chunk * 8 + j) * A_DIM + c];
        const int addr = c * 256 + ((chunk ^ (c & 15)) << 4);
        *reinterpret_cast<f16x8*>(reinterpret_cast<char*>(w1s) + addr) = vh;
    }
    __syncthreads();

    const int lo  = seg_start[b];
    const int len = seg_start[b + 1] - lo;
    const int qper = (((len + SPLIT - 1) / SPLIT) + 63) & ~63;
    const int q0   = q * qper;
    const int qlen = min(qper, len - q0);
    const int ntl  = (qlen + 63) >> 6;        // 64-row tiles in this quarter

    const int lane = tid & 63;
    const int wv   = tid >> 6;
    const int lc   = lane & 15;               // row within 16-row strip
    const int lg   = lane >> 4;               // 0..3 ; k-group
    const int rowoff = q0 + wv * 16 + lc;

    float den = 0.0f;
    float o_part[32];                         // dims ks*32 + lg*8 + j
    #pragma unroll
    for (int v = 0; v < 32; ++v) o_part[v] = 0.0f;

    float4 bufA[8], bufB[8];
    if (ntl > 0) {
        const int gi = min(lo + rowoff, N - 1);
        const float4* xr = reinterpret_cast<const float4*>(x + (size_t)gi * D_DIM);
        #pragma unroll
        for (int ks = 0; ks < 4; ++ks) {
            bufA[2*ks]   = xr[ks*8 + lg*2];
            bufA[2*ks+1] = xr[ks*8 + lg*2 + 1];
        }
    }

// one tile step: consume CUR (f32), prefetch tile T+1 into NXT, accumulate
#define PROC_TILE(CUR, NXT, T)                                                 \
    {                                                                          \
        /* hi-split: packed f32->f16 (rtz; residual never used) */             \
        f16x8 ah[4];                                                           \
        _Pragma("unroll")                                                      \
        for (int ks = 0; ks < 4; ++ks) {                                       \
            union { f16x8 v; fp16x2 h[4]; } u;                                 \
            u.h[0] = __builtin_amdgcn_cvt_pkrtz(CUR[2*ks].x,   CUR[2*ks].y);   \
            u.h[1] = __builtin_amdgcn_cvt_pkrtz(CUR[2*ks].z,   CUR[2*ks].w);   \
            u.h[2] = __builtin_amdgcn_cvt_pkrtz(CUR[2*ks+1].x, CUR[2*ks+1].y); \
            u.h[3] = __builtin_amdgcn_cvt_pkrtz(CUR[2*ks+1].z, CUR[2*ks+1].w); \
            ah[ks] = u.v;                                                      \
        }                                                                      \
        if ((T) + 1 < ntl) {                                                   \
            const int gi = min(lo + rowoff + ((T) + 1) * 64, N - 1);           \
            const float4* xr =                                                 \
                reinterpret_cast<const float4*>(x + (size_t)gi * D_DIM);       \
            _Pragma("unroll")                                                  \
            for (int ks = 0; ks < 4; ++ks) {                                   \
                NXT[2*ks]   = xr[ks*8 + lg*2];                                 \
                NXT[2*ks+1] = xr[ks*8 + lg*2 + 1];                             \
            }                                                                  \
        }                                                                      \
        __builtin_amdgcn_s_setprio(1);                                         \
        float part0 = 0.f, part1 = 0.f, part2 = 0.f, part3 = 0.f;              \
        _Pragma("unroll")                                                      \
        for (int tt = 0; tt < 8; ++tt) {                                       \
            f32x4 acc = {0.f, 0.f, 0.f, 0.f};                                  \
            const int c = tt * 16 + lc;                                        \
            const char* base = reinterpret_cast<const char*>(w1s) + c * 256;   \
            _Pragma("unroll")                                                  \
            for (int ks = 0; ks < 4; ++ks) {                                   \
                const int chunk = ks * 4 + lg;                                 \
                f16x8 bh = *reinterpret_cast<const f16x8*>(                    \
                    base + ((chunk ^ (c & 15)) << 4));                         \
                acc = __builtin_amdgcn_mfma_f32_16x16x32_f16(ah[ks], bh, acc,  \
                                                             0, 0, 0);         \
            }                                                                  \
            const float b1v = sB1[c], w2v = sW2[c];                            \
            part0 += fast_tanh(acc[0] + b1v) * w2v;                            \
            part1 += fast_tanh(acc[1] + b1v) * w2v;                            \
            part2 += fast_tanh(acc[2] + b1v) * w2v;                            \
            part3 += fast_tanh(acc[3] + b1v) * w2v;                            \
        }                                                                      \
        __builtin_amdgcn_s_setprio(0);                                         \
        _Pragma("unroll")                                                      \
        for (int mk = 8; mk >= 1; mk >>= 1) {                                  \
            part0 += __shfl_xor(part0, mk);                                    \
            part1 += __shfl_xor(part1, mk);                                    \
            part2 += __shfl_xor(part2, mk);                                    \
            part3 += __shfl_xor(part3, mk);                                    \
        }                                                                      \
        if (lc == 0) {                                                         \
            float* sl = &s_sc[wv * 16 + lg * 4];                               \
            sl[0] = part0; sl[1] = part1; sl[2] = part2; sl[3] = part3;        \
        }                                                                      \
        const float my_s = s_sc[wv * 16 + lc];                                 \
        const float w = (rowoff + (T) * 64 < len) ? __expf(my_s) : 0.0f;       \
        den += w;                                                              \
        _Pragma("unroll")                                                      \
        for (int ks = 0; ks < 4; ++ks) {                                       \
            o_part[ks*8+0] = fmaf(w, CUR[2*ks].x,   o_part[ks*8+0]);           \
            o_part[ks*8+1] = fmaf(w, CUR[2*ks].y,   o_part[ks*8+1]);           \
            o_part[ks*8+2] = fmaf(w, CUR[2*ks].z,   o_part[ks*8+2]);           \
            o_part[ks*8+3] = fmaf(w, CUR[2*ks].w,   o_part[ks*8+3]);           \
            o_part[ks*8+4] = fmaf(w, CUR[2*ks+1].x, o_part[ks*8+4]);           \
            o_part[ks*8+5] = fmaf(w, CUR[2*ks+1].y, o_part[ks*8+5]);           \
            o_part[ks*8+6] = fmaf(w, CUR[2*ks+1].z, o_part[ks*8+6]);           \
            o_part[ks*8+7] = fmaf(w, CUR[2*ks+1].w, o_part[ks*8+7]);           \
        }                                                                      \
    }

    for (int t = 0; t < ntl; t += 2) {
        PROC_TILE(bufA, bufB, t);
        if (t + 1 < ntl) {
            PROC_TILE(bufB, bufA, t + 1);
        }
    }
#undef PROC_TILE

    // ---- epilogue (single barrier): merge this block's 4 waves ----
    #pragma unroll
    for (int v = 0; v < 32; ++v) {
        #pragma unroll
        for (int mk = 8; mk >= 1; mk >>= 1)
            o_part[v] += __shfl_xor(o_part[v], mk);
    }
    #pragma unroll
    for (int mk = 8; mk >= 1; mk >>= 1) den += __shfl_xor(den, mk);

    if (lc == 0) {
        #pragma unroll
        for (int v = 0; v < 32; ++v)
            o_red[(wv * 4 + lg) * 32 + v] = o_part[v];
        if (lg == 0) s_d[wv] = den;
    }
    __syncthreads();

    float* pb = part + (size_t)blockIdx.x * PSTRIDE;
    if (tid < 128) {
        const int lg2 = tid >> 5, v = tid & 31;
        float val = 0.0f;
        #pragma unroll
        for (int w2 = 0; w2 < NWAVES; ++w2) val += o_red[(w2 * 4 + lg2) * 32 + v];
        const int d = (v >> 3) * 32 + lg2 * 8 + (v & 7);
        pb[d] = val;
        if (tid == 0)
            pb[128] = s_d[0] + s_d[1] + s_d[2] + s_d[3];
    }
}

// K2: sum SPLIT unnormalized partials per segment, normalize.
extern "C" __global__ void __launch_bounds__(128)
combine_kernel(const float* __restrict__ part, float* __restrict__ out)
{
    const int b = blockIdx.x, d = threadIdx.x;
    const float* pb = part + (size_t)b * SPLIT * PSTRIDE;

    float den = 0.0f, val = 0.0f;
    #pragma unroll
    for (int q = 0; q < SPLIT; ++q) {
        den += pb[q * PSTRIDE + 128];
        val += pb[q * PSTRIDE + d];
    }
    out[b * D_DIM + d] = (den > 0.0f) ? val / den : 0.0f;
}

extern "C" void kernel_launch(void* const* d_in, const int* in_sizes, int n_in,
                              void* d_out, int out_size, void* d_ws, size_t ws_size,
                              hipStream_t stream)
{
    const float* x    = (const float*)d_in[0];
    const int*   bidx = (const int*)d_in[1];
    const float* W1   = (const float*)d_in[2];
    const float* b1   = (const float*)d_in[3];
    const float* W2   = (const float*)d_in[4];
    // d_in[5] = b2: cancels in softmax, unused

    const int N = in_sizes[1];
    const int B = out_size / D_DIM;

    char* ws = (char*)d_ws;
    int*   seg_start = (int*)ws;                       // B+1 ints
    float* part      = (float*)(ws + 4096);            // B*SPLIT*PSTRIDE floats

    seg_bounds_kernel<<<(B + 256) / 256, 256, 0, stream>>>(bidx, N, B, seg_start);
    fused_partial_kernel<<<B * SPLIT, NTHREADS, 0, stream>>>(
        x, seg_start, W1, b1, W2, part, N);
    combine_kernel<<<B, 128, 0, stream>>>(part, (float*)d_out);
}

// Round 13
// 82.706 us; speedup vs baseline: 1.2430x; 1.2430x over previous
//
#include <hip/hip_runtime.h>
#include <math.h>

#define D_DIM 128
#define A_DIM 128
#define SPLIT 4            // contiguous quarters per segment
#define NTHREADS 256       // 4 waves per block
#define NWAVES 4
#define PSTRIDE 132        // floats per partial record: o[128], den, pad

typedef _Float16 f16x8 __attribute__((ext_vector_type(8)));
typedef __fp16   fp16x2 __attribute__((ext_vector_type(2)));  // cvt_pkrtz return type
typedef __attribute__((ext_vector_type(4))) float f32x4;

__device__ __forceinline__ float fast_tanh(float v) {
    float e = __expf(2.0f * v);
    return 1.0f - 2.0f * __builtin_amdgcn_rcpf(e + 1.0f);
}

__device__ __forceinline__ int lower_bound_i32(const int* __restrict__ arr, int n, int val) {
    int lo = 0, hi = n;
    while (lo < hi) {
        int mid = (lo + hi) >> 1;
        if (arr[mid] < val) lo = mid + 1; else hi = mid;
    }
    return lo;
}

// K0: parallel segment bounds (bidx sorted)
extern "C" __global__ void __launch_bounds__(256)
seg_bounds_kernel(const int* __restrict__ bidx, int N, int B,
                  int* __restrict__ seg_start)
{
    const int i = blockIdx.x * 256 + threadIdx.x;
    if (i <= B) seg_start[i] = lower_bound_i32(bidx, N, i);
}

// K1: R9 structure + R11 arithmetic diet, without R11's register cost.
//  - single buf[8] f32; consumed ONLY by the 16-op pkrtz split at tile top,
//    then immediately refilled by the prefetch (short lifetime, ~110 VGPR)
//  - ONE fp16 MFMA term (R12 run proved absmax unchanged without al)
//  - o_part accumulates w*(float)ah[j]: output fp16-quantized (~5e-4), in budget
//  - contiguous quarters, barrier-free loop, LDS own-score slot, setprio (R9)
extern "C" __global__ void __launch_bounds__(NTHREADS)
fused_partial_kernel(const float* __restrict__ x,
                     const int* __restrict__ seg_start,
                     const float* __restrict__ W1,
                     const float* __restrict__ b1,
                     const float* __restrict__ W2,
                     float* __restrict__ part,
                     int N)
{
    __shared__ _Float16 w1s[A_DIM * D_DIM];   // 32 KB, [col][k] XOR-swizzled
    __shared__ float sB1[A_DIM];
    __shared__ float sW2[A_DIM];
    __shared__ float s_sc[NWAVES * 16];       // per-wave own-row score slots
    __shared__ float o_red[NWAVES * 4 * 32];  // 2 KB epilogue reduce
    __shared__ float s_d[NWAVES];

    const int tid = threadIdx.x;
    const int b   = blockIdx.x >> 2;          // segment  (SPLIT = 4)
    const int q   = blockIdx.x & (SPLIT - 1); // quarter

    if (tid < A_DIM) { sB1[tid] = b1[tid]; sW2[tid] = W2[tid]; }

    // stage W1: read coalesced [k][c], write transposed+swizzled fp16
    for (int item = tid; item < A_DIM * 16; item += NTHREADS) {
        const int c = item & (A_DIM - 1);
        const int chunk = item >> 7;          // 16B chunk along k (0..15)
        f16x8 vh;
        #pragma unroll
        for (int j = 0; j < 8; ++j)
            vh[j] = (_Float16)W1[(chunk * 8 + j) * A_DIM + c];
        const int addr = c * 256 + ((chunk ^ (c & 15)) << 4);
        *reinterpret_cast<f16x8*>(reinterpret_cast<char*>(w1s) + addr) = vh;
    }
    __syncthreads();

    const int lo  = seg_start[b];
    const int len = seg_start[b + 1] - lo;
    const int qper = (((len + SPLIT - 1) / SPLIT) + 63) & ~63;
    const int q0   = q * qper;
    const int qlen = min(qper, len - q0);
    const int ntl  = (qlen + 63) >> 6;        // 64-row tiles in this quarter

    const int lane = tid & 63;
    const int wv   = tid >> 6;
    const int lc   = lane & 15;               // row within 16-row strip
    const int lg   = lane >> 4;               // 0..3 ; k-group
    const int rowoff = q0 + wv * 16 + lc;

    float den = 0.0f;
    float o_part[32];                         // dims ks*32 + lg*8 + j
    #pragma unroll
    for (int v = 0; v < 32; ++v) o_part[v] = 0.0f;

    float4 buf[8];
    if (ntl > 0) {
        const int gi = min(lo + rowoff, N - 1);
        const float4* xr = reinterpret_cast<const float4*>(x + (size_t)gi * D_DIM);
        #pragma unroll
        for (int ks = 0; ks < 4; ++ks) {
            buf[2*ks]   = xr[ks*8 + lg*2];
            buf[2*ks+1] = xr[ks*8 + lg*2 + 1];
        }
    }

    for (int t = 0; t < ntl; ++t) {
        // ---- split buf -> single fp16 frag set (16 packed cvts), buf freed
        f16x8 ah[4];
        #pragma unroll
        for (int ks = 0; ks < 4; ++ks) {
            union { f16x8 v; fp16x2 h[4]; } u;
            u.h[0] = __builtin_amdgcn_cvt_pkrtz(buf[2*ks].x,   buf[2*ks].y);
            u.h[1] = __builtin_amdgcn_cvt_pkrtz(buf[2*ks].z,   buf[2*ks].w);
            u.h[2] = __builtin_amdgcn_cvt_pkrtz(buf[2*ks+1].x, buf[2*ks+1].y);
            u.h[3] = __builtin_amdgcn_cvt_pkrtz(buf[2*ks+1].z, buf[2*ks+1].w);
            ah[ks] = u.v;
        }

        // ---- prefetch next tile into buf (in-flight through the compute)
        if (t + 1 < ntl) {
            const int gi = min(lo + rowoff + (t + 1) * 64, N - 1);
            const float4* xr = reinterpret_cast<const float4*>(x + (size_t)gi * D_DIM);
            #pragma unroll
            for (int ks = 0; ks < 4; ++ks) {
                buf[2*ks]   = xr[ks*8 + lg*2];
                buf[2*ks+1] = xr[ks*8 + lg*2 + 1];
            }
        }

        // ---- scores via MFMA: this wave's 16 rows x 128 cols ----
        __builtin_amdgcn_s_setprio(1);
        float part0 = 0.f, part1 = 0.f, part2 = 0.f, part3 = 0.f;
        #pragma unroll
        for (int tt = 0; tt < 8; ++tt) {
            f32x4 acc = {0.f, 0.f, 0.f, 0.f};
            const int c = tt * 16 + lc;
            const char* base = reinterpret_cast<const char*>(w1s) + c * 256;
            #pragma unroll
            for (int ks = 0; ks < 4; ++ks) {
                const int chunk = ks * 4 + lg;
                f16x8 bh = *reinterpret_cast<const f16x8*>(
                    base + ((chunk ^ (c & 15)) << 4));
                acc = __builtin_amdgcn_mfma_f32_16x16x32_f16(ah[ks], bh, acc, 0, 0, 0);
            }
            const float b1v = sB1[c], w2v = sW2[c];
            part0 += fast_tanh(acc[0] + b1v) * w2v;
            part1 += fast_tanh(acc[1] + b1v) * w2v;
            part2 += fast_tanh(acc[2] + b1v) * w2v;
            part3 += fast_tanh(acc[3] + b1v) * w2v;
        }
        __builtin_amdgcn_s_setprio(0);

        // reduce over 16 lc lanes -> lane group lg holds rows lg*4+r
        #pragma unroll
        for (int mk = 8; mk >= 1; mk >>= 1) {
            part0 += __shfl_xor(part0, mk);
            part1 += __shfl_xor(part1, mk);
            part2 += __shfl_xor(part2, mk);
            part3 += __shfl_xor(part3, mk);
        }
        // own-row score via per-wave LDS slot (same-wave write->read)
        if (lc == 0) {
            float* sl = &s_sc[wv * 16 + lg * 4];
            sl[0] = part0; sl[1] = part1; sl[2] = part2; sl[3] = part3;
        }
        const float my_s = s_sc[wv * 16 + lc];
        const float w = (rowoff + t * 64 < len) ? __expf(my_s) : 0.0f;
        den += w;

        // ---- accumulate w * fp16(x) from the frags (cvt + fmaf per elem) ----
        #pragma unroll
        for (int ks = 0; ks < 4; ++ks) {
            #pragma unroll
            for (int j = 0; j < 8; ++j)
                o_part[ks*8+j] = fmaf(w, (float)ah[ks][j], o_part[ks*8+j]);
        }
    }

    // ---- epilogue (single barrier): merge this block's 4 waves ----
    #pragma unroll
    for (int v = 0; v < 32; ++v) {
        #pragma unroll
        for (int mk = 8; mk >= 1; mk >>= 1)
            o_part[v] += __shfl_xor(o_part[v], mk);
    }
    #pragma unroll
    for (int mk = 8; mk >= 1; mk >>= 1) den += __shfl_xor(den, mk);

    if (lc == 0) {
        #pragma unroll
        for (int v = 0; v < 32; ++v)
            o_red[(wv * 4 + lg) * 32 + v] = o_part[v];
        if (lg == 0) s_d[wv] = den;
    }
    __syncthreads();

    float* pb = part + (size_t)blockIdx.x * PSTRIDE;
    if (tid < 128) {
        const int lg2 = tid >> 5, v = tid & 31;
        float val = 0.0f;
        #pragma unroll
        for (int w2 = 0; w2 < NWAVES; ++w2) val += o_red[(w2 * 4 + lg2) * 32 + v];
        const int d = (v >> 3) * 32 + lg2 * 8 + (v & 7);
        pb[d] = val;
        if (tid == 0)
            pb[128] = s_d[0] + s_d[1] + s_d[2] + s_d[3];
    }
}

// K2: sum SPLIT unnormalized partials per segment, normalize.
extern "C" __global__ void __launch_bounds__(128)
combine_kernel(const float* __restrict__ part, float* __restrict__ out)
{
    const int b = blockIdx.x, d = threadIdx.x;
    const float* pb = part + (size_t)b * SPLIT * PSTRIDE;

    float den = 0.0f, val = 0.0f;
    #pragma unroll
    for (int q = 0; q < SPLIT; ++q) {
        den += pb[q * PSTRIDE + 128];
        val += pb[q * PSTRIDE + d];
    }
    out[b * D_DIM + d] = (den > 0.0f) ? val / den : 0.0f;
}

extern "C" void kernel_launch(void* const* d_in, const int* in_sizes, int n_in,
                              void* d_out, int out_size, void* d_ws, size_t ws_size,
                              hipStream_t stream)
{
    const float* x    = (const float*)d_in[0];
    const int*   bidx = (const int*)d_in[1];
    const float* W1   = (const float*)d_in[2];
    const float* b1   = (const float*)d_in[3];
    const float* W2   = (const float*)d_in[4];
    // d_in[5] = b2: cancels in softmax, unused

    const int N = in_sizes[1];
    const int B = out_size / D_DIM;

    char* ws = (char*)d_ws;
    int*   seg_start = (int*)ws;                       // B+1 ints
    float* part      = (float*)(ws + 4096);            // B*SPLIT*PSTRIDE floats

    seg_bounds_kernel<<<(B + 256) / 256, 256, 0, stream>>>(bidx, N, B, seg_start);
    fused_partial_kernel<<<B * SPLIT, NTHREADS, 0, stream>>>(
        x, seg_start, W1, b1, W2, part, N);
    combine_kernel<<<B, 128, 0, stream>>>(part, (float*)d_out);
}